// Round 9
// baseline (190.421 us; speedup 1.0000x reference)
//
#include <hip/hip_runtime.h>
#include <math.h>

// NeighborList: P = N*(N-1)/2 triu pairs, minimum-image distance, cutoff mask.
// out layout (float32, concatenated): [P] pair_i, [P] pair_j, [P*3] pair_diff, [P] pair_dist
//
// R9: exploit output sparsity (~0.3% of pairs are within cutoff at
// CUTOFF=5, BOX=55): pair_diff and pair_dist ([2P,6P), 537 MB) are 99.7%
// zeros -> hipMemsetAsync them at the fill engine's ~6.7 TB/s (measured in
// our own profile), then the kernel dense-writes only pair_i/pair_j
// (268 MB, -1.0f or index, not memset-able) and scatter-writes the rare
// unmasked diff/dist entries (~2 MB). Kernel store work (~48 us) roughly
// covers its compute floor (~35 us); memset covers the rest at peak rate.
// Carried: int32+f32 solve_ij, reciprocal-mul min-image (rint-safe: flips
// only possible near |delta|~box/2 where the pair is masked either way),
// diag-cell fast path (off-axis terms are d - s*0 == d bit-exactly).

#define NL_CUTOFF 5.0f

// i,j from linear triu pair index p (int32 domain: P < 2^31).
__device__ __forceinline__ void solve_ij(int p, int N, int& io, int& jo) {
    const int A = 2 * N - 1;
    const int disc = A * A - 8 * p;                 // exact, >= 9
    const float sd = __fsqrt_rn((float)disc);
    int ii = (int)(__fmul_rn(__fsub_rn((float)A, sd), 0.5f));
    if (ii < 0) ii = 0;
    if (ii > N - 2) ii = N - 2;
    while (ii > 0 && ((ii * (A - ii)) >> 1) > p) --ii;
    while ((((ii + 1) * (A - ii - 1)) >> 1) <= p) ++ii;
    io = ii;
    jo = p - ((ii * (A - ii)) >> 1) + ii + 1;
}

struct CellC {
    float r0x, r0y, r0z, rc0;
    float r1x, r1y, r1z, rc1;
    float r2x, r2y, r2z, rc2;
};

template <bool DIAG>
__device__ __forceinline__ void pair_compute(
    float xi, float yi, float zi, float xj, float yj, float zj,
    const CellC& c,
    float& odx, float& ody, float& odz, float& orr, bool& om)
{
    float dx = __fsub_rn(xi, xj);
    float dy = __fsub_rn(yi, yj);
    float dz = __fsub_rn(zi, zj);

    if (DIAG) {
        // diagonal cell: off-axis updates are d - s*0 == d bit-exactly
        float s = rintf(__fmul_rn(dz, c.rc2));
        dz = __fsub_rn(dz, __fmul_rn(s, c.r2z));
        s = rintf(__fmul_rn(dy, c.rc1));
        dy = __fsub_rn(dy, __fmul_rn(s, c.r1y));
        s = rintf(__fmul_rn(dx, c.rc0));
        dx = __fsub_rn(dx, __fmul_rn(s, c.r0x));
    } else {
        float s = rintf(__fmul_rn(dz, c.rc2));
        dx = __fsub_rn(dx, __fmul_rn(s, c.r2x));
        dy = __fsub_rn(dy, __fmul_rn(s, c.r2y));
        dz = __fsub_rn(dz, __fmul_rn(s, c.r2z));

        s = rintf(__fmul_rn(dy, c.rc1));
        dx = __fsub_rn(dx, __fmul_rn(s, c.r1x));
        dy = __fsub_rn(dy, __fmul_rn(s, c.r1y));
        dz = __fsub_rn(dz, __fmul_rn(s, c.r1z));

        s = rintf(__fmul_rn(dx, c.rc0));
        dx = __fsub_rn(dx, __fmul_rn(s, c.r0x));
        dy = __fsub_rn(dy, __fmul_rn(s, c.r0y));
        dz = __fsub_rn(dz, __fmul_rn(s, c.r0z));
    }

    float ss = __fadd_rn(__fadd_rn(__fmul_rn(dx, dx), __fmul_rn(dy, dy)),
                         __fmul_rn(dz, dz));
    float r = __fsqrt_rn(ss);      // correctly rounded: mask boundary bit-exact
    om  = (r < NL_CUTOFF);
    odx = dx;
    ody = dy;
    odz = dz;
    orr = r;
}

template <bool DIAG>
__device__ __forceinline__ void nl_body(
    const float* __restrict__ xyz, const CellC& c,
    float* __restrict__ out, long long P, int N)
{
    float* __restrict__ out_i = out;
    float* __restrict__ out_j = out + P;
    float* __restrict__ out_d = out + 2 * P;   // [P,3] row-major (pre-zeroed)
    float* __restrict__ out_r = out + 5 * P;   // (pre-zeroed)

    const long long nquad  = P >> 2;
    const long long stride = (long long)gridDim.x * blockDim.x;
    const long long tid0   = (long long)blockIdx.x * blockDim.x + threadIdx.x;

    for (long long q = tid0; q < nquad; q += stride) {
        int i, j;
        solve_ij((int)(q << 2), N, i, j);

        float dxa[4], dya[4], dza[4], ra[4];
        bool  ma[4];
        float oia[4], oja[4];
        if (j + 3 <= N - 1) {
            const float xi = xyz[3 * i + 0], yi = xyz[3 * i + 1], zi = xyz[3 * i + 2];
            const float fi = (float)i, fj = (float)j;
#pragma unroll
            for (int k = 0; k < 4; ++k) {
                pair_compute<DIAG>(xi, yi, zi,
                                   xyz[3 * (j + k) + 0], xyz[3 * (j + k) + 1],
                                   xyz[3 * (j + k) + 2],
                                   c, dxa[k], dya[k], dza[k], ra[k], ma[k]);
                oia[k] = ma[k] ? fi : -1.0f;
                oja[k] = ma[k] ? fj + (float)k : -1.0f;
            }
        } else {
            int ii = i, jj = j;
#pragma unroll
            for (int k = 0; k < 4; ++k) {
                pair_compute<DIAG>(xyz[3 * ii + 0], xyz[3 * ii + 1], xyz[3 * ii + 2],
                                   xyz[3 * jj + 0], xyz[3 * jj + 1], xyz[3 * jj + 2],
                                   c, dxa[k], dya[k], dza[k], ra[k], ma[k]);
                oia[k] = ma[k] ? (float)ii : -1.0f;
                oja[k] = ma[k] ? (float)jj : -1.0f;
                if (++jj >= N) { ++ii; jj = ii + 1; }
            }
        }

        // dense i/j streams: contiguous float4 per lane
        ((float4*)out_i)[q] = make_float4(oia[0], oia[1], oia[2], oia[3]);
        ((float4*)out_j)[q] = make_float4(oja[0], oja[1], oja[2], oja[3]);

        // sparse diff/dist: regions pre-zeroed by memset, write only hits
        if (ma[0] | ma[1] | ma[2] | ma[3]) {
#pragma unroll
            for (int k = 0; k < 4; ++k) {
                if (ma[k]) {
                    const long long p = (q << 2) + k;
                    out_d[3 * p + 0] = dxa[k];
                    out_d[3 * p + 1] = dya[k];
                    out_d[3 * p + 2] = dza[k];
                    out_r[p]         = ra[k];
                }
            }
        }
    }

    // tail (P % 4 != 0 safety; P divisible by 4 for N=8192)
    for (long long p = (nquad << 2) + tid0; p < P; p += stride) {
        int i, j;
        solve_ij((int)p, N, i, j);
        float dx, dy, dz, rr;
        bool  m;
        pair_compute<DIAG>(xyz[3 * i + 0], xyz[3 * i + 1], xyz[3 * i + 2],
                           xyz[3 * j + 0], xyz[3 * j + 1], xyz[3 * j + 2],
                           c, dx, dy, dz, rr, m);
        out_i[p] = m ? (float)i : -1.0f;
        out_j[p] = m ? (float)j : -1.0f;
        if (m) {
            out_d[3 * p + 0] = dx;
            out_d[3 * p + 1] = dy;
            out_d[3 * p + 2] = dz;
            out_r[p]         = rr;
        }
    }
}

__global__ __launch_bounds__(256) void nl_kernel(
    const float* __restrict__ xyz,
    const float* __restrict__ cell,
    float* __restrict__ out,
    long long P, int N)
{
    CellC c;
    c.r0x = cell[0]; c.r0y = cell[1]; c.r0z = cell[2];
    c.r1x = cell[3]; c.r1y = cell[4]; c.r1z = cell[5];
    c.r2x = cell[6]; c.r2y = cell[7]; c.r2z = cell[8];
    c.rc0 = __fdiv_rn(1.0f, c.r0x);
    c.rc1 = __fdiv_rn(1.0f, c.r1y);
    c.rc2 = __fdiv_rn(1.0f, c.r2z);

    const bool diag = (c.r0y == 0.0f) && (c.r0z == 0.0f) &&
                      (c.r1x == 0.0f) && (c.r1z == 0.0f) &&
                      (c.r2x == 0.0f) && (c.r2y == 0.0f);

    if (diag) nl_body<true>(xyz, c, out, P, N);
    else      nl_body<false>(xyz, c, out, P, N);
}

extern "C" void kernel_launch(void* const* d_in, const int* in_sizes, int n_in,
                              void* d_out, int out_size, void* d_ws, size_t ws_size,
                              hipStream_t stream) {
    const float* xyz  = (const float*)d_in[0];
    const float* cell = (const float*)d_in[1];
    float* out = (float*)d_out;

    const int       N = in_sizes[0] / 3;
    const long long P = (long long)in_sizes[2];

    // zero pair_diff + pair_dist ([2P,6P), 4P floats) at fill-engine rate;
    // the kernel then scatter-writes only the ~0.3% unmasked entries.
    hipMemsetAsync(out + 2 * P, 0, (size_t)(4 * P) * sizeof(float), stream);

    const int block = 256;
    long long nquad = P >> 2;
    long long blocks_needed = (nquad + block - 1) / block;
    int grid = (int)(blocks_needed < 2048 ? (blocks_needed > 0 ? blocks_needed : 1)
                                          : 2048);

    nl_kernel<<<grid, block, 0, stream>>>(xyz, cell, out, P, N);
}

// Round 10
// 159.650 us; speedup vs baseline: 1.1927x; 1.1927x over previous
//
#include <hip/hip_runtime.h>
#include <math.h>

// NeighborList: P = N*(N-1)/2 triu pairs, minimum-image distance, cutoff mask.
// out layout (float32, concatenated): [P] pair_i, [P] pair_j, [P*3] pair_diff, [P] pair_dist
//
// R10 = R8 (dense writes, per-wave LDS transpose of the diff stream) with the
// j-side gather vectorized IN PLACE: the quad's 4 atoms are 12 consecutive
// floats at xyz+3j -> three dwordx4 loads (4B-aligned vector loads are legal)
// instead of 12 scalar dwords. Cuts L1/TA line transactions ~4x; R9 measured
// ~60-70us of exposed load cost competing with store issue through TA.
// (R9's memset split regressed: graph serializes memset(80us)+kernel(110us).)
// Carried: int32+f32 solve_ij, reciprocal-mul min-image (rint-safe: flips
// only possible near |delta|~box/2 where the pair is masked either way),
// diag-cell fast path (off-axis terms are d - s*0 == d bit-exactly).

#define NL_CUTOFF 5.0f

typedef float f32x4 __attribute__((ext_vector_type(4)));

// i,j from linear triu pair index p (int32 domain: P < 2^31).
__device__ __forceinline__ void solve_ij(int p, int N, int& io, int& jo) {
    const int A = 2 * N - 1;
    const int disc = A * A - 8 * p;                 // exact, >= 9
    const float sd = __fsqrt_rn((float)disc);
    int ii = (int)(__fmul_rn(__fsub_rn((float)A, sd), 0.5f));
    if (ii < 0) ii = 0;
    if (ii > N - 2) ii = N - 2;
    while (ii > 0 && ((ii * (A - ii)) >> 1) > p) --ii;
    while ((((ii + 1) * (A - ii - 1)) >> 1) <= p) ++ii;
    io = ii;
    jo = p - ((ii * (A - ii)) >> 1) + ii + 1;
}

struct CellC {
    float r0x, r0y, r0z, rc0;
    float r1x, r1y, r1z, rc1;
    float r2x, r2y, r2z, rc2;
};

template <bool DIAG>
__device__ __forceinline__ void pair_compute(
    float xi, float yi, float zi, float xj, float yj, float zj,
    const CellC& c, float fi, float fj,
    float& oi, float& oj, float& odx, float& ody, float& odz, float& orr)
{
    float dx = __fsub_rn(xi, xj);
    float dy = __fsub_rn(yi, yj);
    float dz = __fsub_rn(zi, zj);

    if (DIAG) {
        // diagonal cell: off-axis updates are d - s*0 == d bit-exactly
        float s = rintf(__fmul_rn(dz, c.rc2));
        dz = __fsub_rn(dz, __fmul_rn(s, c.r2z));
        s = rintf(__fmul_rn(dy, c.rc1));
        dy = __fsub_rn(dy, __fmul_rn(s, c.r1y));
        s = rintf(__fmul_rn(dx, c.rc0));
        dx = __fsub_rn(dx, __fmul_rn(s, c.r0x));
    } else {
        float s = rintf(__fmul_rn(dz, c.rc2));
        dx = __fsub_rn(dx, __fmul_rn(s, c.r2x));
        dy = __fsub_rn(dy, __fmul_rn(s, c.r2y));
        dz = __fsub_rn(dz, __fmul_rn(s, c.r2z));

        s = rintf(__fmul_rn(dy, c.rc1));
        dx = __fsub_rn(dx, __fmul_rn(s, c.r1x));
        dy = __fsub_rn(dy, __fmul_rn(s, c.r1y));
        dz = __fsub_rn(dz, __fmul_rn(s, c.r1z));

        s = rintf(__fmul_rn(dx, c.rc0));
        dx = __fsub_rn(dx, __fmul_rn(s, c.r0x));
        dy = __fsub_rn(dy, __fmul_rn(s, c.r0y));
        dz = __fsub_rn(dz, __fmul_rn(s, c.r0z));
    }

    float ss = __fadd_rn(__fadd_rn(__fmul_rn(dx, dx), __fmul_rn(dy, dy)),
                         __fmul_rn(dz, dz));
    float r = __fsqrt_rn(ss);      // correctly rounded: mask boundary bit-exact
    bool m = (r < NL_CUTOFF);

    oi  = m ? fi : -1.0f;
    oj  = m ? fj : -1.0f;
    odx = m ? dx : 0.0f;
    ody = m ? dy : 0.0f;
    odz = m ? dz : 0.0f;
    orr = m ? r  : 0.0f;
}

template <bool DIAG>
__device__ __forceinline__ void nl_body(
    const float* __restrict__ xyz, const CellC& c,
    float* __restrict__ out, long long P, int N,
    f32x4* __restrict__ wslab)          // per-wave 192-float4 LDS slab
{
    float* __restrict__ out_i = out;
    float* __restrict__ out_j = out + P;
    float* __restrict__ out_d = out + 2 * P;   // [P,3] row-major
    float* __restrict__ out_r = out + 5 * P;

    const long long nquad  = P >> 2;
    const long long stride = (long long)gridDim.x * blockDim.x;
    const long long tid0   = (long long)blockIdx.x * blockDim.x + threadIdx.x;
    const int       lane   = (int)(threadIdx.x & 63);
    const int       lm     = lane % 3;

    for (long long q = tid0; q < nquad; q += stride) {
        int i, j;
        solve_ij((int)(q << 2), N, i, j);

        float oia[4], oja[4], ora[4], od[12];
        if (j + 3 <= N - 1) {
            const float xi = xyz[3 * i + 0], yi = xyz[3 * i + 1], zi = xyz[3 * i + 2];
            const float fi = (float)i, fj = (float)j;

            // 12 consecutive floats at xyz+3j = the 4 j-atoms; 3 vector loads
            const float* jb = xyz + 3 * j;
            f32x4 va, vb, vc;
            __builtin_memcpy(&va, jb + 0, 16);
            __builtin_memcpy(&vb, jb + 4, 16);
            __builtin_memcpy(&vc, jb + 8, 16);
            const float jx[4] = {va.x, va.w, vb.z, vc.y};
            const float jy[4] = {va.y, vb.x, vb.w, vc.z};
            const float jz[4] = {va.z, vb.y, vc.x, vc.w};
#pragma unroll
            for (int k = 0; k < 4; ++k) {
                pair_compute<DIAG>(xi, yi, zi, jx[k], jy[k], jz[k],
                                   c, fi, fj + (float)k,
                                   oia[k], oja[k], od[3 * k + 0], od[3 * k + 1],
                                   od[3 * k + 2], ora[k]);
            }
        } else {
            int ii = i, jj = j;
#pragma unroll
            for (int k = 0; k < 4; ++k) {
                pair_compute<DIAG>(xyz[3 * ii + 0], xyz[3 * ii + 1], xyz[3 * ii + 2],
                                   xyz[3 * jj + 0], xyz[3 * jj + 1], xyz[3 * jj + 2],
                                   c, (float)ii, (float)jj,
                                   oia[k], oja[k], od[3 * k + 0], od[3 * k + 1],
                                   od[3 * k + 2], ora[k]);
                if (++jj >= N) { ++ii; jj = ii + 1; }
            }
        }

        ((float4*)out_i)[q] = make_float4(oia[0], oia[1], oia[2], oia[3]);
        ((float4*)out_j)[q] = make_float4(oja[0], oja[1], oja[2], oja[3]);
        ((float4*)out_r)[q] = make_float4(ora[0], ora[1], ora[2], ora[3]);

        const f32x4 pd0 = {od[0], od[1], od[2],  od[3]};
        const f32x4 pd1 = {od[4], od[5], od[6],  od[7]};
        const f32x4 pd2 = {od[8], od[9], od[10], od[11]};

        const long long qw = q - lane;              // wave-uniform base quad
        if (qw + 63 < nquad) {
            // wave fully active: LDS transpose -> lane-contiguous dd stores.
            int s0 = lm;
            int s1 = lm + 1; if (s1 >= 3) s1 -= 3;
            int s2 = lm + 2; if (s2 >= 3) s2 -= 3;
            wslab[3 * lane + s0] = pd0;
            wslab[3 * lane + s1] = pd1;
            wslab[3 * lane + s2] = pd2;
            __builtin_amdgcn_wave_barrier();
            f32x4* __restrict__ dd4 = (f32x4*)out_d;   // 16B-aligned (P%4==0)
#pragma unroll
            for (int m = 0; m < 3; ++m) {
                const int f  = m * 64 + lane;          // flat float4 idx in wave tile
                const int r  = f / 3;                  // owner lane
                const int cc = f - 3 * r;              // component
                int s = cc + r % 3; if (s >= 3) s -= 3;
                const f32x4 v = wslab[3 * r + s];
                dd4[3 * qw + f] = v;                   // contiguous 1KB/instr
            }
            __builtin_amdgcn_wave_barrier();
        } else {
            float4* dd = (float4*)(out_d + 12 * q);
            dd[0] = make_float4(od[0], od[1],  od[2],  od[3]);
            dd[1] = make_float4(od[4], od[5],  od[6],  od[7]);
            dd[2] = make_float4(od[8], od[9],  od[10], od[11]);
        }
    }

    // tail (P % 4 != 0 safety; P divisible by 4 for N=8192)
    for (long long p = (nquad << 2) + tid0; p < P; p += stride) {
        int i, j;
        solve_ij((int)p, N, i, j);
        float oi, oj, dx, dy, dz, rr;
        pair_compute<DIAG>(xyz[3 * i + 0], xyz[3 * i + 1], xyz[3 * i + 2],
                           xyz[3 * j + 0], xyz[3 * j + 1], xyz[3 * j + 2],
                           c, (float)i, (float)j, oi, oj, dx, dy, dz, rr);
        out_i[p] = oi;
        out_j[p] = oj;
        out_d[3 * p + 0] = dx;
        out_d[3 * p + 1] = dy;
        out_d[3 * p + 2] = dz;
        out_r[p] = rr;
    }
}

__global__ __launch_bounds__(256) void nl_kernel(
    const float* __restrict__ xyz,
    const float* __restrict__ cell,
    float* __restrict__ out,
    long long P, int N)
{
    __shared__ f32x4 slab[4][192];     // one 3KB slab per wave (block = 4 waves)

    CellC c;
    c.r0x = cell[0]; c.r0y = cell[1]; c.r0z = cell[2];
    c.r1x = cell[3]; c.r1y = cell[4]; c.r1z = cell[5];
    c.r2x = cell[6]; c.r2y = cell[7]; c.r2z = cell[8];
    c.rc0 = __fdiv_rn(1.0f, c.r0x);
    c.rc1 = __fdiv_rn(1.0f, c.r1y);
    c.rc2 = __fdiv_rn(1.0f, c.r2z);

    const bool diag = (c.r0y == 0.0f) && (c.r0z == 0.0f) &&
                      (c.r1x == 0.0f) && (c.r1z == 0.0f) &&
                      (c.r2x == 0.0f) && (c.r2y == 0.0f);

    const int wid = threadIdx.x >> 6;
    if (diag) nl_body<true>(xyz, c, out, P, N, slab[wid]);
    else      nl_body<false>(xyz, c, out, P, N, slab[wid]);
}

extern "C" void kernel_launch(void* const* d_in, const int* in_sizes, int n_in,
                              void* d_out, int out_size, void* d_ws, size_t ws_size,
                              hipStream_t stream) {
    const float* xyz  = (const float*)d_in[0];
    const float* cell = (const float*)d_in[1];
    float* out = (float*)d_out;

    const int       N = in_sizes[0] / 3;
    const long long P = (long long)in_sizes[2];

    const int block = 256;
    long long nquad = P >> 2;
    long long blocks_needed = (nquad + block - 1) / block;
    int grid = (int)(blocks_needed < 2048 ? (blocks_needed > 0 ? blocks_needed : 1)
                                          : 2048);

    nl_kernel<<<grid, block, 0, stream>>>(xyz, cell, out, P, N);
}